// Round 2
// baseline (773.156 us; speedup 1.0000x reference)
//
#include <hip/hip_runtime.h>
#include <hip/hip_bf16.h>
#include <math.h>

#define NN 50000
#define ROWS 32
#define NHID 256

typedef __bf16 bf16_t;
typedef __bf16 bf16x8 __attribute__((ext_vector_type(8)));
typedef float f32x4 __attribute__((ext_vector_type(4)));

static __device__ inline f32x4 mfma16(bf16x8 a, bf16x8 b, f32x4 c) {
  return __builtin_amdgcn_mfma_f32_16x16x32_bf16(a, b, c, 0, 0, 0);
}

static __device__ inline float sigm(float z) { return 1.f / (1.f + __expf(-z)); }
static __device__ inline float tanh_fast(float z) {
  z = fminf(fmaxf(z, -15.f), 15.f);
  float e = __expf(2.f * z);
  return (e - 1.f) / (e + 1.f);
}

// ---------------- prep v2: LDS-transpose tiles, coalesced both sides ----------------
// wtg layout: [gate][n=0..255][k=0..511]  (k<256: W_g[k][n], k>=256: Th_g[k-256][n])
// wtl layout: [n=0..255][k=0..255]        (W_lin[k][n])
// biasg: [gate][n] = bth_g[n] + b_g[n]
__global__ __launch_bounds__(256)
void prep_kernel(const float* __restrict__ Wi, const float* __restrict__ Wf,
                 const float* __restrict__ Wc, const float* __restrict__ Wo,
                 const float* __restrict__ Ti, const float* __restrict__ Tf,
                 const float* __restrict__ Tc, const float* __restrict__ To,
                 const float* __restrict__ Wl,
                 const float* __restrict__ bthi, const float* __restrict__ bthf,
                 const float* __restrict__ bthc, const float* __restrict__ btho,
                 const float* __restrict__ bi, const float* __restrict__ bfv,
                 const float* __restrict__ bc, const float* __restrict__ bo,
                 bf16_t* __restrict__ wtg, bf16_t* __restrict__ wtl,
                 float* __restrict__ biasg) {
  const int b = blockIdx.x;
  const int tid = threadIdx.x;
  if (b == 144) {  // biases
    if (tid < 256) {
#pragma unroll
      for (int g = 0; g < 4; ++g) {
        const float* bt = (g == 0) ? bthi : (g == 1) ? bthf : (g == 2) ? bthc : btho;
        const float* bb = (g == 0) ? bi : (g == 1) ? bfv : (g == 2) ? bc : bo;
        biasg[g * 256 + tid] = bt[tid] + bb[tid];
      }
    }
    return;
  }
  // 64x64 transpose tile: matrices 0-3 = W_g (k-offset 0), 4-7 = Th_g (k-offset 256), 8 = W_lin
  const int m = b >> 4;        // matrix 0..8
  const int t = b & 15;        // tile 0..15
  const int k0 = (t >> 2) * 64;
  const int n0 = (t & 3) * 64;
  const float* S =
      (m == 0) ? Wi : (m == 1) ? Wf : (m == 2) ? Wc : (m == 3) ? Wo :
      (m == 4) ? Ti : (m == 5) ? Tf : (m == 6) ? Tc : (m == 7) ? To : Wl;
  bf16_t* D = (m < 8) ? (wtg + ((m & 3) * 256) * 512) : wtl;
  const int ldd = (m < 8) ? 512 : 256;
  const int kb = (m >= 4 && m < 8) ? 256 : 0;

  __shared__ float tile[64][65];
#pragma unroll
  for (int it = 0; it < 16; ++it) {
    int p = it * 256 + tid;
    int row = p >> 6, col = p & 63;
    tile[row][col] = S[(k0 + row) * 256 + (n0 + col)];
  }
  __syncthreads();
#pragma unroll
  for (int it = 0; it < 16; ++it) {
    int p = it * 256 + tid;
    int nl = p >> 6, kl = p & 63;
    D[(n0 + nl) * ldd + kb + k0 + kl] = (bf16_t)tile[kl][nl];
  }
}

// ---------------- main fused kernel ----------------
// One block = 32 rows, 256 threads (4 waves). Wave w owns output cols [w*64,w*64+64).
// X=[x|h] bf16 in 32KB LDS (XOR swizzle). c prefetched to regs once. 4 gate GEMMs
// (K=512) + fused LSTM math, then relu(H) @ W_lin through LDS.
__global__ __launch_bounds__(256, 4)
void gclstm_kernel(const float* __restrict__ x, const float* __restrict__ hin,
                   const float* __restrict__ cin,
                   const bf16_t* __restrict__ wtg, const bf16_t* __restrict__ wtl,
                   const float* __restrict__ biasg,
                   const float* __restrict__ wci, const float* __restrict__ wcf,
                   const float* __restrict__ wco, const float* __restrict__ blin,
                   float* __restrict__ dout) {
  __shared__ __align__(16) char smem[ROWS * 1024];

  const int tid = threadIdx.x;
  const int lane = tid & 63;
  const int w = tid >> 6;
  const int r0 = blockIdx.x * ROWS;

  const int rl = lane & 15;            // A-row / B-col / D-col within 16-tile
  const int ko = (lane >> 4) * 8;      // k offset within 32-chunk
  const int wc0 = w * 64;              // this wave's first output column
  const int rowoff = (lane >> 4) * 4;  // D-row offset within 16-tile

  // ---- prefetch this wave's c tile into regs (issue before staging; used after GEMM i) ----
  float cv[2][4][4];
#pragma unroll
  for (int rt = 0; rt < 2; ++rt) {
#pragma unroll
    for (int j = 0; j < 4; ++j) {
      int r = r0 + rt * 16 + rowoff + j;
      int rc = (r < NN) ? r : (NN - 1);
#pragma unroll
      for (int ct = 0; ct < 4; ++ct)
        cv[rt][ct][j] = cin[rc * NHID + wc0 + ct * 16 + rl];
    }
  }

  // ---- stage X = [x|h] as bf16 into LDS, XOR swizzle byte ^= (row&7)<<4 ----
#pragma unroll
  for (int it = 0; it < 8; ++it) {
    int p = it * 256 + tid;
    int row = p >> 6;
    int ce = (p & 63) * 8;  // element column 0..504 in the 512-wide X row
    int grow = r0 + row;
    grow = (grow < NN) ? grow : (NN - 1);
    const float* src = (ce < 256) ? (x + grow * 256 + ce) : (hin + grow * 256 + (ce - 256));
    float4 v0 = *reinterpret_cast<const float4*>(src);
    float4 v1 = *reinterpret_cast<const float4*>(src + 4);
    bf16x8 o;
    o[0] = (bf16_t)v0.x; o[1] = (bf16_t)v0.y; o[2] = (bf16_t)v0.z; o[3] = (bf16_t)v0.w;
    o[4] = (bf16_t)v1.x; o[5] = (bf16_t)v1.y; o[6] = (bf16_t)v1.z; o[7] = (bf16_t)v1.w;
    int byte = row * 1024 + ((ce * 2) ^ ((row & 7) << 4));
    *reinterpret_cast<bf16x8*>(smem + byte) = o;
  }
  __syncthreads();

  f32x4 acc[2][4];
  f32x4 st[2][4];

#define XADDR(ROW, COLE) \
  reinterpret_cast<const bf16x8*>(smem + (ROW) * 1024 + ((((COLE) * 2)) ^ (((ROW) & 7) << 4)))

#define GATE_MM(G)                                                                        \
  {                                                                                       \
    const bf16_t* wb = wtg + ((G) * 256 + wc0 + rl) * 512 + ko;                           \
    _Pragma("unroll") for (int rt = 0; rt < 2; ++rt)                                      \
        _Pragma("unroll") for (int ct = 0; ct < 4; ++ct)                                  \
            acc[rt][ct] = f32x4{0.f, 0.f, 0.f, 0.f};                                      \
    _Pragma("unroll") for (int ks = 0; ks < 16; ++ks) {                                   \
      bf16x8 afr[2], bfr[4];                                                              \
      _Pragma("unroll") for (int rt = 0; rt < 2; ++rt)                                    \
          afr[rt] = *XADDR(rt * 16 + rl, ks * 32 + ko);                                   \
      _Pragma("unroll") for (int ct = 0; ct < 4; ++ct)                                    \
          bfr[ct] = *reinterpret_cast<const bf16x8*>(wb + ct * 16 * 512 + ks * 32);       \
      _Pragma("unroll") for (int rt = 0; rt < 2; ++rt)                                    \
          _Pragma("unroll") for (int ct = 0; ct < 4; ++ct)                                \
              acc[rt][ct] = mfma16(afr[rt], bfr[ct], acc[rt][ct]);                        \
    }                                                                                     \
  }

  // ---------- gate i ----------
  GATE_MM(0);
#pragma unroll
  for (int ct = 0; ct < 4; ++ct) {
    int col = wc0 + ct * 16 + rl;
    float wciv = wci[col];
    float bv = biasg[col];
#pragma unroll
    for (int rt = 0; rt < 2; ++rt)
#pragma unroll
      for (int j = 0; j < 4; ++j)
        st[rt][ct][j] = sigm(acc[rt][ct][j] + wciv * cv[rt][ct][j] + bv);  // st = I
  }

  // ---------- gate c (candidate) ----------
  GATE_MM(2);
#pragma unroll
  for (int ct = 0; ct < 4; ++ct) {
    int col = wc0 + ct * 16 + rl;
    float bv = biasg[2 * 256 + col];
#pragma unroll
    for (int rt = 0; rt < 2; ++rt)
#pragma unroll
      for (int j = 0; j < 4; ++j)
        st[rt][ct][j] *= tanh_fast(acc[rt][ct][j] + bv);  // st = I*T
  }

  // ---------- gate f ----------
  GATE_MM(1);
#pragma unroll
  for (int ct = 0; ct < 4; ++ct) {
    int col = wc0 + ct * 16 + rl;
    float wcfv = wcf[col];
    float bv = biasg[256 + col];
#pragma unroll
    for (int rt = 0; rt < 2; ++rt)
#pragma unroll
      for (int j = 0; j < 4; ++j) {
        float fg = sigm(acc[rt][ct][j] + wcfv * cv[rt][ct][j] + bv);
        st[rt][ct][j] = fg * cv[rt][ct][j] + st[rt][ct][j];  // st = C
      }
  }
  // store c0 (clustered per row: 4 back-to-back 64B stores)
#pragma unroll
  for (int rt = 0; rt < 2; ++rt)
#pragma unroll
    for (int j = 0; j < 4; ++j) {
      int r = r0 + rt * 16 + rowoff + j;
      if (r < NN) {
#pragma unroll
        for (int ct = 0; ct < 4; ++ct)
          dout[2 * NN * NHID + r * NHID + wc0 + ct * 16 + rl] = st[rt][ct][j];
      }
    }

  // ---------- gate o ----------
  GATE_MM(3);
#pragma unroll
  for (int ct = 0; ct < 4; ++ct) {
    int col = wc0 + ct * 16 + rl;
    float wcov = wco[col];
    float bv = biasg[3 * 256 + col];
#pragma unroll
    for (int rt = 0; rt < 2; ++rt)
#pragma unroll
      for (int j = 0; j < 4; ++j) {
        float C = st[rt][ct][j];
        float O = sigm(acc[rt][ct][j] + wcov * C + bv);
        st[rt][ct][j] = O * tanh_fast(C);  // st = H
      }
  }
  // store h0 (clustered)
#pragma unroll
  for (int rt = 0; rt < 2; ++rt)
#pragma unroll
    for (int j = 0; j < 4; ++j) {
      int r = r0 + rt * 16 + rowoff + j;
      if (r < NN) {
#pragma unroll
        for (int ct = 0; ct < 4; ++ct)
          dout[NN * NHID + r * NHID + wc0 + ct * 16 + rl] = st[rt][ct][j];
      }
    }

  // ---------- exchange relu(H) through LDS (aliases X buffer) ----------
  __syncthreads();  // all waves done reading X tile
  bf16_t* ht = reinterpret_cast<bf16_t*>(smem);  // [32][264]
#pragma unroll
  for (int ct = 0; ct < 4; ++ct)
#pragma unroll
    for (int rt = 0; rt < 2; ++rt)
#pragma unroll
      for (int j = 0; j < 4; ++j)
        ht[(rt * 16 + rowoff + j) * 264 + wc0 + ct * 16 + rl] =
            (bf16_t)fmaxf(st[rt][ct][j], 0.f);
  __syncthreads();

  // ---------- out = relu(H) @ W_lin + b_lin ----------
#pragma unroll
  for (int rt = 0; rt < 2; ++rt)
#pragma unroll
    for (int ct = 0; ct < 4; ++ct) acc[rt][ct] = f32x4{0.f, 0.f, 0.f, 0.f};
  {
    const bf16_t* wlb = wtl + (wc0 + rl) * 256 + ko;
#pragma unroll
    for (int ks = 0; ks < 8; ++ks) {
      bf16x8 afr[2], bfr[4];
#pragma unroll
      for (int rt = 0; rt < 2; ++rt)
        afr[rt] = *reinterpret_cast<const bf16x8*>(&ht[(rt * 16 + rl) * 264 + ks * 32 + ko]);
#pragma unroll
      for (int ct = 0; ct < 4; ++ct)
        bfr[ct] = *reinterpret_cast<const bf16x8*>(wlb + ct * 16 * 256 + ks * 32);
#pragma unroll
      for (int rt = 0; rt < 2; ++rt)
#pragma unroll
        for (int ct = 0; ct < 4; ++ct)
          acc[rt][ct] = mfma16(afr[rt], bfr[ct], acc[rt][ct]);
    }
  }
#pragma unroll
  for (int rt = 0; rt < 2; ++rt)
#pragma unroll
    for (int j = 0; j < 4; ++j) {
      int r = r0 + rt * 16 + rowoff + j;
      if (r < NN) {
#pragma unroll
        for (int ct = 0; ct < 4; ++ct) {
          int col = wc0 + ct * 16 + rl;
          dout[r * NHID + col] = acc[rt][ct][j] + blin[col];
        }
      }
    }
#undef GATE_MM
#undef XADDR
}

extern "C" void kernel_launch(void* const* d_in, const int* in_sizes, int n_in,
                              void* d_out, int out_size, void* d_ws, size_t ws_size,
                              hipStream_t stream) {
  const float* x = (const float*)d_in[0];
  // d_in[1] edge_index, d_in[2] edge_weight: mathematically unused (K=1 ChebConv)
  const float* h = (const float*)d_in[3];
  const float* c = (const float*)d_in[4];
  const float* Wi = (const float*)d_in[5];
  const float* Wf = (const float*)d_in[6];
  const float* Wc = (const float*)d_in[7];
  const float* Wo = (const float*)d_in[8];
  const float* Ti = (const float*)d_in[9];
  const float* Tf = (const float*)d_in[10];
  const float* Tc = (const float*)d_in[11];
  const float* To = (const float*)d_in[12];
  const float* bthi = (const float*)d_in[13];
  const float* bthf = (const float*)d_in[14];
  const float* bthc = (const float*)d_in[15];
  const float* btho = (const float*)d_in[16];
  const float* wci = (const float*)d_in[17];
  const float* wcf = (const float*)d_in[18];
  const float* wco = (const float*)d_in[19];
  const float* bi = (const float*)d_in[20];
  const float* bfv = (const float*)d_in[21];
  const float* bc = (const float*)d_in[22];
  const float* bo = (const float*)d_in[23];
  const float* Wl = (const float*)d_in[24];
  const float* blin = (const float*)d_in[25];

  char* ws = (char*)d_ws;
  bf16_t* wtg = (bf16_t*)ws;                          // 4*256*512*2 = 1,048,576 B
  bf16_t* wtl = (bf16_t*)(ws + 4 * 256 * 512 * 2);    // 256*256*2 = 131,072 B
  float* biasg = (float*)(ws + 4 * 256 * 512 * 2 + 256 * 256 * 2);  // 4*256*4 B

  prep_kernel<<<145, 256, 0, stream>>>(Wi, Wf, Wc, Wo, Ti, Tf, Tc, To, Wl,
                                       bthi, bthf, bthc, btho, bi, bfv, bc, bo,
                                       wtg, wtl, biasg);

  int grid = (NN + ROWS - 1) / ROWS;  // 1563
  gclstm_kernel<<<grid, 256, 0, stream>>>(x, h, c, wtg, wtl, biasg,
                                          wci, wcf, wco, blin, (float*)d_out);
}

// Round 3
// 571.642 us; speedup vs baseline: 1.3525x; 1.3525x over previous
//
#include <hip/hip_runtime.h>
#include <hip/hip_bf16.h>
#include <math.h>

#define NN 50000
#define ROWS 32
#define NHID 256

typedef __bf16 bf16_t;
typedef __bf16 bf16x4 __attribute__((ext_vector_type(4)));
typedef __bf16 bf16x8 __attribute__((ext_vector_type(8)));
typedef float f32x4 __attribute__((ext_vector_type(4)));

static __device__ inline f32x4 mfma16(bf16x8 a, bf16x8 b, f32x4 c) {
  return __builtin_amdgcn_mfma_f32_16x16x32_bf16(a, b, c, 0, 0, 0);
}

static __device__ inline float sigm(float z) { return 1.f / (1.f + __expf(-z)); }
static __device__ inline float tanh_fast(float z) {
  z = fminf(fmaxf(z, -15.f), 15.f);
  float e = __expf(2.f * z);
  return (e - 1.f) / (e + 1.f);
}

// ---------------- prep: LDS-transpose tiles, coalesced both sides ----------------
// wtg layout: [gate][n=0..255][k=0..511]  (k<256: W_g[k][n], k>=256: Th_g[k-256][n])
// wtl layout: [n=0..255][k=0..255]        (W_lin[k][n])
// biasg: [gate][n] = bth_g[n] + b_g[n]
__global__ __launch_bounds__(256)
void prep_kernel(const float* __restrict__ Wi, const float* __restrict__ Wf,
                 const float* __restrict__ Wc, const float* __restrict__ Wo,
                 const float* __restrict__ Ti, const float* __restrict__ Tf,
                 const float* __restrict__ Tc, const float* __restrict__ To,
                 const float* __restrict__ Wl,
                 const float* __restrict__ bthi, const float* __restrict__ bthf,
                 const float* __restrict__ bthc, const float* __restrict__ btho,
                 const float* __restrict__ bi, const float* __restrict__ bfv,
                 const float* __restrict__ bc, const float* __restrict__ bo,
                 bf16_t* __restrict__ wtg, bf16_t* __restrict__ wtl,
                 float* __restrict__ biasg) {
  const int b = blockIdx.x;
  const int tid = threadIdx.x;
  if (b == 144) {  // biases
    if (tid < 256) {
#pragma unroll
      for (int g = 0; g < 4; ++g) {
        const float* bt = (g == 0) ? bthi : (g == 1) ? bthf : (g == 2) ? bthc : btho;
        const float* bb = (g == 0) ? bi : (g == 1) ? bfv : (g == 2) ? bc : bo;
        biasg[g * 256 + tid] = bt[tid] + bb[tid];
      }
    }
    return;
  }
  // 64x64 transpose tile: matrices 0-3 = W_g (k-offset 0), 4-7 = Th_g (k-offset 256), 8 = W_lin
  const int m = b >> 4;        // matrix 0..8
  const int t = b & 15;        // tile 0..15
  const int k0 = (t >> 2) * 64;
  const int n0 = (t & 3) * 64;
  const float* S =
      (m == 0) ? Wi : (m == 1) ? Wf : (m == 2) ? Wc : (m == 3) ? Wo :
      (m == 4) ? Ti : (m == 5) ? Tf : (m == 6) ? Tc : (m == 7) ? To : Wl;
  bf16_t* D = (m < 8) ? (wtg + ((m & 3) * 256) * 512) : wtl;
  const int ldd = (m < 8) ? 512 : 256;
  const int kb = (m >= 4 && m < 8) ? 256 : 0;

  __shared__ float tile[64][65];
#pragma unroll
  for (int it = 0; it < 16; ++it) {
    int p = it * 256 + tid;
    int row = p >> 6, col = p & 63;
    tile[row][col] = S[(k0 + row) * 256 + (n0 + col)];
  }
  __syncthreads();
#pragma unroll
  for (int it = 0; it < 16; ++it) {
    int p = it * 256 + tid;
    int nl = p >> 6, kl = p & 63;
    D[(n0 + nl) * ldd + kb + k0 + kl] = (bf16_t)tile[kl][nl];
  }
}

// ---------------- main fused kernel ----------------
// One block = 32 rows, 256 threads (4 waves). Wave w owns output cols [w*64,w*64+64).
// X=[x|h] bf16 in 32KB LDS (XOR swizzle). c prefetched once into bf16-packed regs.
// 4 gate GEMMs (K=512) + fused LSTM math, then relu(H) @ W_lin through LDS.
// launch_bounds(256,3): VGPR cap ~170 — enough for acc+st+cv+frags with NO spills
// (round-2's (256,4) cap of 128 caused 1.2GB of scratch traffic).
__global__ __launch_bounds__(256, 3)
void gclstm_kernel(const float* __restrict__ x, const float* __restrict__ hin,
                   const float* __restrict__ cin,
                   const bf16_t* __restrict__ wtg, const bf16_t* __restrict__ wtl,
                   const float* __restrict__ biasg,
                   const float* __restrict__ wci, const float* __restrict__ wcf,
                   const float* __restrict__ wco, const float* __restrict__ blin,
                   float* __restrict__ dout) {
  __shared__ __align__(16) char smem[ROWS * 1024];

  const int tid = threadIdx.x;
  const int lane = tid & 63;
  const int w = tid >> 6;
  const int r0 = blockIdx.x * ROWS;

  const int rl = lane & 15;            // A-row / B-col / D-col within 16-tile
  const int ko = (lane >> 4) * 8;      // k offset within 32-chunk
  const int wc0 = w * 64;              // this wave's first output column
  const int rowoff = (lane >> 4) * 4;  // D-row offset within 16-tile

  // ---- prefetch this wave's c tile ONCE into bf16-packed regs (16 VGPRs) ----
  bf16x4 cvb[2][4];
#pragma unroll
  for (int rt = 0; rt < 2; ++rt) {
#pragma unroll
    for (int j = 0; j < 4; ++j) {
      int r = r0 + rt * 16 + rowoff + j;
      int rc = (r < NN) ? r : (NN - 1);
#pragma unroll
      for (int ct = 0; ct < 4; ++ct)
        cvb[rt][ct][j] = (bf16_t)cin[rc * NHID + wc0 + ct * 16 + rl];
    }
  }

  // ---- stage X = [x|h] as bf16 into LDS, XOR swizzle byte ^= (row&7)<<4 ----
#pragma unroll
  for (int it = 0; it < 8; ++it) {
    int p = it * 256 + tid;
    int row = p >> 6;
    int ce = (p & 63) * 8;  // element column 0..504 in the 512-wide X row
    int grow = r0 + row;
    grow = (grow < NN) ? grow : (NN - 1);
    const float* src = (ce < 256) ? (x + grow * 256 + ce) : (hin + grow * 256 + (ce - 256));
    float4 v0 = *reinterpret_cast<const float4*>(src);
    float4 v1 = *reinterpret_cast<const float4*>(src + 4);
    bf16x8 o;
    o[0] = (bf16_t)v0.x; o[1] = (bf16_t)v0.y; o[2] = (bf16_t)v0.z; o[3] = (bf16_t)v0.w;
    o[4] = (bf16_t)v1.x; o[5] = (bf16_t)v1.y; o[6] = (bf16_t)v1.z; o[7] = (bf16_t)v1.w;
    int byte = row * 1024 + ((ce * 2) ^ ((row & 7) << 4));
    *reinterpret_cast<bf16x8*>(smem + byte) = o;
  }
  __syncthreads();

  f32x4 acc[2][4];
  f32x4 st[2][4];

#define XADDR(ROW, COLE) \
  reinterpret_cast<const bf16x8*>(smem + (ROW) * 1024 + ((((COLE) * 2)) ^ (((ROW) & 7) << 4)))

#define GATE_MM(G)                                                                        \
  {                                                                                       \
    const bf16_t* wb = wtg + ((G) * 256 + wc0 + rl) * 512 + ko;                           \
    _Pragma("unroll") for (int rt = 0; rt < 2; ++rt)                                      \
        _Pragma("unroll") for (int ct = 0; ct < 4; ++ct)                                  \
            acc[rt][ct] = f32x4{0.f, 0.f, 0.f, 0.f};                                      \
    _Pragma("unroll") for (int ks = 0; ks < 16; ++ks) {                                   \
      bf16x8 afr[2], bfr[4];                                                              \
      _Pragma("unroll") for (int rt = 0; rt < 2; ++rt)                                    \
          afr[rt] = *XADDR(rt * 16 + rl, ks * 32 + ko);                                   \
      _Pragma("unroll") for (int ct = 0; ct < 4; ++ct)                                    \
          bfr[ct] = *reinterpret_cast<const bf16x8*>(wb + ct * 16 * 512 + ks * 32);       \
      _Pragma("unroll") for (int rt = 0; rt < 2; ++rt)                                    \
          _Pragma("unroll") for (int ct = 0; ct < 4; ++ct)                                \
              acc[rt][ct] = mfma16(afr[rt], bfr[ct], acc[rt][ct]);                        \
    }                                                                                     \
  }

  // ---------- gate i ----------
  GATE_MM(0);
#pragma unroll
  for (int ct = 0; ct < 4; ++ct) {
    int col = wc0 + ct * 16 + rl;
    float wciv = wci[col];
    float bv = biasg[col];
#pragma unroll
    for (int rt = 0; rt < 2; ++rt)
#pragma unroll
      for (int j = 0; j < 4; ++j)
        st[rt][ct][j] = sigm(acc[rt][ct][j] + wciv * (float)cvb[rt][ct][j] + bv);  // st = I
  }

  // ---------- gate c (candidate) ----------
  GATE_MM(2);
#pragma unroll
  for (int ct = 0; ct < 4; ++ct) {
    int col = wc0 + ct * 16 + rl;
    float bv = biasg[2 * 256 + col];
#pragma unroll
    for (int rt = 0; rt < 2; ++rt)
#pragma unroll
      for (int j = 0; j < 4; ++j)
        st[rt][ct][j] *= tanh_fast(acc[rt][ct][j] + bv);  // st = I*T
  }

  // ---------- gate f ----------
  GATE_MM(1);
#pragma unroll
  for (int ct = 0; ct < 4; ++ct) {
    int col = wc0 + ct * 16 + rl;
    float wcfv = wcf[col];
    float bv = biasg[256 + col];
#pragma unroll
    for (int rt = 0; rt < 2; ++rt)
#pragma unroll
      for (int j = 0; j < 4; ++j) {
        float cv = (float)cvb[rt][ct][j];
        float fg = sigm(acc[rt][ct][j] + wcfv * cv + bv);
        st[rt][ct][j] = fg * cv + st[rt][ct][j];  // st = C
      }
  }
  // store c0 (clustered per row: 4 back-to-back 64B stores → 256B contiguous per wave)
#pragma unroll
  for (int rt = 0; rt < 2; ++rt)
#pragma unroll
    for (int j = 0; j < 4; ++j) {
      int r = r0 + rt * 16 + rowoff + j;
      if (r < NN) {
#pragma unroll
        for (int ct = 0; ct < 4; ++ct)
          dout[2 * NN * NHID + r * NHID + wc0 + ct * 16 + rl] = st[rt][ct][j];
      }
    }

  // ---------- gate o ----------
  GATE_MM(3);
#pragma unroll
  for (int ct = 0; ct < 4; ++ct) {
    int col = wc0 + ct * 16 + rl;
    float wcov = wco[col];
    float bv = biasg[3 * 256 + col];
#pragma unroll
    for (int rt = 0; rt < 2; ++rt)
#pragma unroll
      for (int j = 0; j < 4; ++j) {
        float C = st[rt][ct][j];
        float O = sigm(acc[rt][ct][j] + wcov * C + bv);
        st[rt][ct][j] = O * tanh_fast(C);  // st = H
      }
  }
  // store h0 (clustered)
#pragma unroll
  for (int rt = 0; rt < 2; ++rt)
#pragma unroll
    for (int j = 0; j < 4; ++j) {
      int r = r0 + rt * 16 + rowoff + j;
      if (r < NN) {
#pragma unroll
        for (int ct = 0; ct < 4; ++ct)
          dout[NN * NHID + r * NHID + wc0 + ct * 16 + rl] = st[rt][ct][j];
      }
    }

  // ---------- exchange relu(H) through LDS (aliases X buffer) ----------
  __syncthreads();  // all waves done reading X tile
  bf16_t* ht = reinterpret_cast<bf16_t*>(smem);  // [32][264]
#pragma unroll
  for (int ct = 0; ct < 4; ++ct)
#pragma unroll
    for (int rt = 0; rt < 2; ++rt)
#pragma unroll
      for (int j = 0; j < 4; ++j)
        ht[(rt * 16 + rowoff + j) * 264 + wc0 + ct * 16 + rl] =
            (bf16_t)fmaxf(st[rt][ct][j], 0.f);
  __syncthreads();

  // ---------- out = relu(H) @ W_lin + b_lin ----------
#pragma unroll
  for (int rt = 0; rt < 2; ++rt)
#pragma unroll
    for (int ct = 0; ct < 4; ++ct) acc[rt][ct] = f32x4{0.f, 0.f, 0.f, 0.f};
  {
    const bf16_t* wlb = wtl + (wc0 + rl) * 256 + ko;
#pragma unroll
    for (int ks = 0; ks < 8; ++ks) {
      bf16x8 afr[2], bfr[4];
#pragma unroll
      for (int rt = 0; rt < 2; ++rt)
        afr[rt] = *reinterpret_cast<const bf16x8*>(&ht[(rt * 16 + rl) * 264 + ks * 32 + ko]);
#pragma unroll
      for (int ct = 0; ct < 4; ++ct)
        bfr[ct] = *reinterpret_cast<const bf16x8*>(wlb + ct * 16 * 256 + ks * 32);
#pragma unroll
      for (int rt = 0; rt < 2; ++rt)
#pragma unroll
        for (int ct = 0; ct < 4; ++ct)
          acc[rt][ct] = mfma16(afr[rt], bfr[ct], acc[rt][ct]);
    }
  }
#pragma unroll
  for (int rt = 0; rt < 2; ++rt)
#pragma unroll
    for (int j = 0; j < 4; ++j) {
      int r = r0 + rt * 16 + rowoff + j;
      if (r < NN) {
#pragma unroll
        for (int ct = 0; ct < 4; ++ct) {
          int col = wc0 + ct * 16 + rl;
          dout[r * NHID + col] = acc[rt][ct][j] + blin[col];
        }
      }
    }
#undef GATE_MM
#undef XADDR
}

extern "C" void kernel_launch(void* const* d_in, const int* in_sizes, int n_in,
                              void* d_out, int out_size, void* d_ws, size_t ws_size,
                              hipStream_t stream) {
  const float* x = (const float*)d_in[0];
  // d_in[1] edge_index, d_in[2] edge_weight: mathematically unused (K=1 ChebConv)
  const float* h = (const float*)d_in[3];
  const float* c = (const float*)d_in[4];
  const float* Wi = (const float*)d_in[5];
  const float* Wf = (const float*)d_in[6];
  const float* Wc = (const float*)d_in[7];
  const float* Wo = (const float*)d_in[8];
  const float* Ti = (const float*)d_in[9];
  const float* Tf = (const float*)d_in[10];
  const float* Tc = (const float*)d_in[11];
  const float* To = (const float*)d_in[12];
  const float* bthi = (const float*)d_in[13];
  const float* bthf = (const float*)d_in[14];
  const float* bthc = (const float*)d_in[15];
  const float* btho = (const float*)d_in[16];
  const float* wci = (const float*)d_in[17];
  const float* wcf = (const float*)d_in[18];
  const float* wco = (const float*)d_in[19];
  const float* bi = (const float*)d_in[20];
  const float* bfv = (const float*)d_in[21];
  const float* bc = (const float*)d_in[22];
  const float* bo = (const float*)d_in[23];
  const float* Wl = (const float*)d_in[24];
  const float* blin = (const float*)d_in[25];

  char* ws = (char*)d_ws;
  bf16_t* wtg = (bf16_t*)ws;                          // 4*256*512*2 = 1,048,576 B
  bf16_t* wtl = (bf16_t*)(ws + 4 * 256 * 512 * 2);    // 256*256*2 = 131,072 B
  float* biasg = (float*)(ws + 4 * 256 * 512 * 2 + 256 * 256 * 2);  // 4*256*4 B

  prep_kernel<<<145, 256, 0, stream>>>(Wi, Wf, Wc, Wo, Ti, Tf, Tc, To, Wl,
                                       bthi, bthf, bthc, btho, bi, bfv, bc, bo,
                                       wtg, wtl, biasg);

  int grid = (NN + ROWS - 1) / ROWS;  // 1563
  gclstm_kernel<<<grid, 256, 0, stream>>>(x, h, c, wtg, wtl, biasg,
                                          wci, wcf, wco, blin, (float*)d_out);
}

// Round 5
// 440.244 us; speedup vs baseline: 1.7562x; 1.2985x over previous
//
#include <hip/hip_runtime.h>
#include <hip/hip_bf16.h>
#include <math.h>

#define NN 50000

typedef __bf16 bf16_t;
typedef __bf16 bf16x8 __attribute__((ext_vector_type(8)));
typedef float f32x4 __attribute__((ext_vector_type(4)));
typedef unsigned int u32;

static __device__ __forceinline__ f32x4 mfma16(bf16x8 a, bf16x8 b, f32x4 c) {
  return __builtin_amdgcn_mfma_f32_16x16x32_bf16(a, b, c, 0, 0, 0);
}
// async global->LDS, 16B per lane; lds dest = wave-uniform base + lane*16
static __device__ __forceinline__ void gl_lds16(const void* g, void* l) {
  __builtin_amdgcn_global_load_lds((const __attribute__((address_space(1))) u32*)g,
                                   (__attribute__((address_space(3))) u32*)l, 16, 0, 0);
}
static __device__ inline float sigm(float z) { return 1.f / (1.f + __expf(-z)); }
static __device__ inline float tanh_fast(float z) {
  z = fminf(fmaxf(z, -15.f), 15.f);
  float e = __expf(2.f * z);
  return (e - 1.f) / (e + 1.f);
}
// bank-conflict-free 16B-unit placement for B chunk images:
// chunk = [cols c][4 units u of 8k]; unit index = c*4 + ((u + (c>>1)) & 3)
// -> 16 consecutive cols at fixed u hit 8 distinct bank-quads (2-way, free)
static __device__ __forceinline__ int bunit(int c, int u) {
  return c * 4 + ((u + (c >> 1)) & 3);
}
// bijective XCD-aware remap (m204 form)
static __device__ __forceinline__ int xcd_swz(int orig, int nwg) {
  int q = nwg >> 3, r = nwg & 7;
  int x = orig & 7;
  int base = (x < r) ? x * (q + 1) : r * (q + 1) + (x - r) * q;
  return base + (orig >> 3);
}

// ---------------- prep: build B-chunk images (pre-scrambled), bias fold ----------------
// wtg_s: [panel p=0..3][chunk ks=0..15] 16KB images; chunk rows cg = gate*64 + (col&63),
//        32 k-elems each, unit-scrambled via bunit().  k<256: W_g, k>=256: Th_g.
// wtl_s: [chunk ks=0..7] 16KB images, rows c=0..255 (W_lin cols), same scramble.
__global__ __launch_bounds__(256)
void prep_kernel(const float* __restrict__ Wi, const float* __restrict__ Wf,
                 const float* __restrict__ Wc, const float* __restrict__ Wo,
                 const float* __restrict__ Ti, const float* __restrict__ Tf,
                 const float* __restrict__ Tc, const float* __restrict__ To,
                 const float* __restrict__ Wl,
                 const float* __restrict__ bthi, const float* __restrict__ bthf,
                 const float* __restrict__ bthc, const float* __restrict__ btho,
                 const float* __restrict__ bi, const float* __restrict__ bfv,
                 const float* __restrict__ bc, const float* __restrict__ bo,
                 bf16_t* __restrict__ wtg_s, bf16_t* __restrict__ wtl_s,
                 float* __restrict__ biasg) {
  const int b = blockIdx.x;
  const int tid = threadIdx.x;
  if (b == 144) {
#pragma unroll
    for (int g = 0; g < 4; ++g) {
      const float* bt = (g == 0) ? bthi : (g == 1) ? bthf : (g == 2) ? bthc : btho;
      const float* bb = (g == 0) ? bi : (g == 1) ? bfv : (g == 2) ? bc : bo;
      biasg[g * 256 + tid] = bt[tid] + bb[tid];
    }
    return;
  }
  __shared__ float tile[64][65];
  const int isLin = (b >= 128);
  const int m = isLin ? 8 : (b >> 4);
  const int t = isLin ? (b - 128) : (b & 15);
  const int k0 = (t >> 2) * 64, n0 = (t & 3) * 64;
  const float* S =
      (m == 0) ? Wi : (m == 1) ? Wf : (m == 2) ? Wc : (m == 3) ? Wo :
      (m == 4) ? Ti : (m == 5) ? Tf : (m == 6) ? Tc : (m == 7) ? To : Wl;
#pragma unroll
  for (int it = 0; it < 16; ++it) {
    int p2 = it * 256 + tid;
    int row = p2 >> 6, col = p2 & 63;
    tile[row][col] = S[(k0 + row) * 256 + (n0 + col)];
  }
  __syncthreads();
#pragma unroll
  for (int it = 0; it < 2; ++it) {
    int q = it * 256 + tid;  // 0..511 : 64 cols x 8 k-units
    int nl = q >> 3, u8 = q & 7;
    bf16x8 o;
#pragma unroll
    for (int e = 0; e < 8; ++e) o[e] = (bf16_t)tile[u8 * 8 + e][nl];
    if (!isLin) {
      int kbase = (m >= 4) ? 256 : 0, g = m & 3, p = n0 >> 6;
      int kg = kbase + k0 + u8 * 8;
      int ks = kg >> 5, u = (kg >> 3) & 3;
      int cg = g * 64 + nl;
      *(bf16x8*)((char*)wtg_s + (p * 16 + ks) * 16384 + bunit(cg, u) * 16) = o;
    } else {
      int c = n0 + nl;
      int kg = k0 + u8 * 8;
      int ks = kg >> 5, u = (kg >> 3) & 3;
      *(bf16x8*)((char*)wtl_s + ks * 16384 + bunit(c, u) * 16) = o;
    }
  }
}

// ---------------- convert: Xb = bf16([x | h]), row-major [NN][512] ----------------
__global__ __launch_bounds__(256)
void convert_kernel(const float* __restrict__ x, const float* __restrict__ h,
                    bf16_t* __restrict__ Xb) {
  int id = blockIdx.x * 256 + threadIdx.x;
  if (id >= NN * 64) return;
  int row = id >> 6, ce = (id & 63) * 8;
  const float* s = (ce < 256) ? (x + row * 256 + ce) : (h + row * 256 + (ce - 256));
  float4 a = *reinterpret_cast<const float4*>(s);
  float4 b = *reinterpret_cast<const float4*>(s + 4);
  bf16x8 o;
  o[0] = (bf16_t)a.x; o[1] = (bf16_t)a.y; o[2] = (bf16_t)a.z; o[3] = (bf16_t)a.w;
  o[4] = (bf16_t)b.x; o[5] = (bf16_t)b.y; o[6] = (bf16_t)b.z; o[7] = (bf16_t)b.w;
  *reinterpret_cast<bf16x8*>(Xb + row * 512 + ce) = o;
}

// ---------------- gemm_gates: 4-gate fused GEMM + LSTM epilogue ----------------
// Block = 32 rows x 64 hid cols x 4 gates, K=512. 4 waves: wave = 16r x 32c.
// A (Xb tile) in swizzled LDS (staged once, gl_lds w/ source pre-swizzle).
// B streamed through 3-buffer LDS pipeline, 16KB/chunk, staged 2 ahead,
// counted vmcnt(4) — loads stay in flight across barriers (T3/T4).
__global__ __launch_bounds__(256, 2)
void gemm_gates(const bf16_t* __restrict__ Xb, const float* __restrict__ cin,
                const bf16_t* __restrict__ wtg_s, const float* __restrict__ biasg,
                const float* __restrict__ wci, const float* __restrict__ wcf,
                const float* __restrict__ wco,
                float* __restrict__ dout, bf16_t* __restrict__ relu_h) {
  extern __shared__ char smem[];  // 32KB A + 3x16KB B = 81920
  const int nwg = ((NN + 31) / 32) * 4;  // 6252
  const int wg = xcd_swz(blockIdx.x, nwg);
  const int mt = wg >> 2, panel = wg & 3;
  const int r0 = mt * 32;
  const int tid = threadIdx.x, lane = tid & 63, w = tid >> 6;
  const int rl = lane & 15, u = lane >> 4, ko = u * 8, rowoff = u * 4;
  const int wr = w >> 1, wc = w & 1;

  // c prefetch (overlaps all staging/GEMM; consumed in epilogue)
  float cv[2][4];
#pragma unroll
  for (int ct = 0; ct < 2; ++ct)
#pragma unroll
    for (int j = 0; j < 4; ++j) {
      int r = r0 + wr * 16 + rowoff + j;
      r = (r < NN) ? r : (NN - 1);
      cv[ct][j] = cin[r * 256 + panel * 64 + wc * 32 + ct * 16 + rl];
    }

  char* Abase = smem;
  char* Bb0 = smem + 32768;
  char* Bb1 = smem + 32768 + 16384;
  char* Bb2 = smem + 32768 + 32768;

  // stage A: image[row][kb'] = Xb[row][kb'^((row&7)<<4)] via source pre-swizzle
#pragma unroll
  for (int it = 0; it < 8; ++it) {
    int row = it * 4 + w;
    int rr = r0 + row;
    rr = (rr < NN) ? rr : (NN - 1);
    int swz = (lane * 16) ^ ((row & 7) << 4);
    gl_lds16(Xb + rr * 512 + (swz >> 1), Abase + row * 1024);
  }
#define STAGE_B(KSN, BUF)                                                      \
  {                                                                            \
    const char* src_ = (const char*)wtg_s + (panel * 16 + (KSN)) * 16384;      \
    _Pragma("unroll") for (int j_ = 0; j_ < 4; ++j_)                           \
        gl_lds16(src_ + (j_ * 4 + w) * 1024 + lane * 16,                       \
                 (BUF) + (j_ * 4 + w) * 1024);                                 \
  }
  STAGE_B(0, Bb0);
  STAGE_B(1, Bb1);
  asm volatile("s_waitcnt vmcnt(4)" ::: "memory");  // drain c+A+B0, B1 in flight
  __builtin_amdgcn_s_barrier();
  asm volatile("" ::: "memory");

  f32x4 acc[4][2];
#pragma unroll
  for (int g = 0; g < 4; ++g)
#pragma unroll
    for (int ct = 0; ct < 2; ++ct) acc[g][ct] = f32x4{0.f, 0.f, 0.f, 0.f};

  const int arow = wr * 16 + rl;
  const int axor = (arow & 7) << 4;

#pragma unroll
  for (int ks = 0; ks < 16; ++ks) {
    char* bufs[3] = {Bb0, Bb1, Bb2};
    if (ks + 2 < 16) {
      char* nb = bufs[(ks + 2) % 3];
      STAGE_B(ks + 2, nb);
    }
    bf16x8 afr = *(const bf16x8*)(Abase + arow * 1024 + (((ks * 32 + ko) * 2) ^ axor));
    char* bb = bufs[ks % 3];
    bf16x8 bfr[4][2];
#pragma unroll
    for (int g = 0; g < 4; ++g)
#pragma unroll
      for (int ct = 0; ct < 2; ++ct) {
        int cg = g * 64 + wc * 32 + ct * 16 + rl;
        bfr[g][ct] = *(const bf16x8*)(bb + bunit(cg, u) * 16);
      }
#pragma unroll
    for (int g = 0; g < 4; ++g)
#pragma unroll
      for (int ct = 0; ct < 2; ++ct)
        acc[g][ct] = mfma16(afr, bfr[g][ct], acc[g][ct]);
    if (ks < 15) {
      if (ks < 14) asm volatile("s_waitcnt vmcnt(4)" ::: "memory");
      else         asm volatile("s_waitcnt vmcnt(0)" ::: "memory");
      __builtin_amdgcn_s_barrier();
      asm volatile("" ::: "memory");
    }
  }
#undef STAGE_B

  // fused LSTM epilogue
#pragma unroll
  for (int ct = 0; ct < 2; ++ct) {
    int col = panel * 64 + wc * 32 + ct * 16 + rl;
    float b_i = biasg[col], b_f = biasg[256 + col];
    float b_c = biasg[512 + col], b_o = biasg[768 + col];
    float wciv = wci[col], wcfv = wcf[col], wcov = wco[col];
#pragma unroll
    for (int j = 0; j < 4; ++j) {
      int r = r0 + wr * 16 + rowoff + j;
      float cvj = cv[ct][j];
      float I = sigm(acc[0][ct][j] + wciv * cvj + b_i);
      float Fg = sigm(acc[1][ct][j] + wcfv * cvj + b_f);
      float T = tanh_fast(acc[2][ct][j] + b_c);
      float C = Fg * cvj + I * T;
      float O = sigm(acc[3][ct][j] + wcov * C + b_o);
      float H = O * tanh_fast(C);
      if (r < NN) {
        dout[2 * NN * 256 + r * 256 + col] = C;
        dout[NN * 256 + r * 256 + col] = H;
        relu_h[r * 256 + col] = (bf16_t)fmaxf(H, 0.f);
      }
    }
  }
}

// ---------------- gemm_lin: out = relu(H) @ W_lin + b_lin ----------------
// Block = 32 rows x 256 cols, K=256 (8 chunks). Wave = 16r x 128c (ct=8).
__global__ __launch_bounds__(256, 2)
void gemm_lin(const bf16_t* __restrict__ relu_h, const bf16_t* __restrict__ wtl_s,
              const float* __restrict__ blin, float* __restrict__ dout) {
  extern __shared__ char smem[];  // 16KB A + 3x16KB B = 65536
  const int nwg = (NN + 31) / 32;  // 1563
  const int wg = xcd_swz(blockIdx.x, nwg);
  const int r0 = wg * 32;
  const int tid = threadIdx.x, lane = tid & 63, w = tid >> 6;
  const int rl = lane & 15, u = lane >> 4, ko = u * 8, rowoff = u * 4;
  const int wr = w >> 1, wc = w & 1;

  char* Abase = smem;
  char* Bb0 = smem + 16384;
  char* Bb1 = smem + 32768;
  char* Bb2 = smem + 49152;

  // stage A: rows are 512B; each wave-instr covers 2 rows (lanes 0-31 / 32-63)
#pragma unroll
  for (int it = 0; it < 4; ++it) {
    int seg = it * 4 + w;               // 1KB segment = rows seg*2, seg*2+1
    int row = seg * 2 + (lane >> 5);
    int rr = r0 + row;
    rr = (rr < NN) ? rr : (NN - 1);
    int kb = ((lane & 31) * 16) ^ ((row & 7) << 4);
    gl_lds16(relu_h + rr * 256 + (kb >> 1), Abase + seg * 1024);
  }
#define STAGE_L(KSN, BUF)                                                      \
  {                                                                            \
    const char* src_ = (const char*)wtl_s + (KSN) * 16384;                     \
    _Pragma("unroll") for (int j_ = 0; j_ < 4; ++j_)                           \
        gl_lds16(src_ + (j_ * 4 + w) * 1024 + lane * 16,                       \
                 (BUF) + (j_ * 4 + w) * 1024);                                 \
  }
  STAGE_L(0, Bb0);
  STAGE_L(1, Bb1);
  asm volatile("s_waitcnt vmcnt(4)" ::: "memory");
  __builtin_amdgcn_s_barrier();
  asm volatile("" ::: "memory");

  f32x4 acc[8];
#pragma unroll
  for (int ct = 0; ct < 8; ++ct) acc[ct] = f32x4{0.f, 0.f, 0.f, 0.f};

  const int arow = wr * 16 + rl;
  const int axor = (arow & 7) << 4;

#pragma unroll
  for (int ks = 0; ks < 8; ++ks) {
    char* bufs[3] = {Bb0, Bb1, Bb2};
    if (ks + 2 < 8) {
      char* nb = bufs[(ks + 2) % 3];
      STAGE_L(ks + 2, nb);
    }
    bf16x8 afr = *(const bf16x8*)(Abase + arow * 512 + (((ks * 32 + ko) * 2) ^ axor));
    char* bb = bufs[ks % 3];
#pragma unroll
    for (int ct = 0; ct < 8; ++ct) {
      int c = wc * 128 + ct * 16 + rl;
      bf16x8 bfr = *(const bf16x8*)(bb + bunit(c, u) * 16);
      acc[ct] = mfma16(afr, bfr, acc[ct]);
    }
    if (ks < 7) {
      if (ks < 6) asm volatile("s_waitcnt vmcnt(4)" ::: "memory");
      else        asm volatile("s_waitcnt vmcnt(0)" ::: "memory");
      __builtin_amdgcn_s_barrier();
      asm volatile("" ::: "memory");
    }
  }
#undef STAGE_L

#pragma unroll
  for (int ct = 0; ct < 8; ++ct) {
    int col = wc * 128 + ct * 16 + rl;
    float bl = blin[col];
#pragma unroll
    for (int j = 0; j < 4; ++j) {
      int r = r0 + wr * 16 + rowoff + j;
      if (r < NN) dout[r * 256 + col] = acc[ct][j] + bl;
    }
  }
}

extern "C" void kernel_launch(void* const* d_in, const int* in_sizes, int n_in,
                              void* d_out, int out_size, void* d_ws, size_t ws_size,
                              hipStream_t stream) {
  const float* x = (const float*)d_in[0];
  // d_in[1] edge_index, d_in[2] edge_weight: mathematically unused (K=1 ChebConv)
  const float* h = (const float*)d_in[3];
  const float* c = (const float*)d_in[4];
  const float* Wi = (const float*)d_in[5];
  const float* Wf = (const float*)d_in[6];
  const float* Wc = (const float*)d_in[7];
  const float* Wo = (const float*)d_in[8];
  const float* Ti = (const float*)d_in[9];
  const float* Tf = (const float*)d_in[10];
  const float* Tc = (const float*)d_in[11];
  const float* To = (const float*)d_in[12];
  const float* bthi = (const float*)d_in[13];
  const float* bthf = (const float*)d_in[14];
  const float* bthc = (const float*)d_in[15];
  const float* btho = (const float*)d_in[16];
  const float* wci = (const float*)d_in[17];
  const float* wcf = (const float*)d_in[18];
  const float* wco = (const float*)d_in[19];
  const float* bi = (const float*)d_in[20];
  const float* bfv = (const float*)d_in[21];
  const float* bc = (const float*)d_in[22];
  const float* bo = (const float*)d_in[23];
  const float* Wl = (const float*)d_in[24];
  const float* blin = (const float*)d_in[25];

  char* ws = (char*)d_ws;
  bf16_t* Xb = (bf16_t*)ws;                           // 50000*512*2 = 51,200,000
  bf16_t* relu_h = (bf16_t*)(ws + 51200000);          // 50000*256*2 = 25,600,000
  bf16_t* wtg_s = (bf16_t*)(ws + 76800000);           // 4*16*16384  =  1,048,576
  bf16_t* wtl_s = (bf16_t*)(ws + 77848576);           // 8*16384     =    131,072
  float* biasg = (float*)(ws + 77979648);             // 4*256*4     =      4,096

  prep_kernel<<<145, 256, 0, stream>>>(Wi, Wf, Wc, Wo, Ti, Tf, Tc, To, Wl,
                                       bthi, bthf, bthc, btho, bi, bfv, bc, bo,
                                       wtg_s, wtl_s, biasg);
  convert_kernel<<<12500, 256, 0, stream>>>(x, h, Xb);
  gemm_gates<<<6252, 256, 81920, stream>>>(Xb, c, wtg_s, biasg, wci, wcf, wco,
                                           (float*)d_out, relu_h);
  gemm_lin<<<1563, 256, 65536, stream>>>(relu_h, wtl_s, blin, (float*)d_out);
}